// Round 3
// baseline (2067.150 us; speedup 1.0000x reference)
//
#include <hip/hip_runtime.h>

// EQL forward, round 2 (resubmitted — round-2 bench never acquired a GPU).
//   kernel 1 (mask):  masked weights written TRANSPOSED+PADDED per (s,o):
//                     layout [layer][e][d_pad] so every row is 16B-aligned -> d_ws
//   kernel 2 (main):  one block per (s,o,chunk); weights staged to LDS once,
//                     read back as broadcast ds_read_b128. hidden[96] in VGPRs.
//   kernel 3 (fin):   out[983040] = regu_sum / (S*B*O)

#define S_NUM 16
#define O_NUM 15
#define B_NUM 4096
#define NET_IN 64
#define WSHAPE 3120
#define BSHAPE 41
#define WPAD 3184              // padded transposed size per (s,o)
#define BIAS_OFF WPAD          // bias offset inside LDS
#define TEMP_F 0.03f
#define EPS_F 1e-20f
#define OUT_ELEMS (S_NUM * B_NUM * O_NUM)   // 983040

// ---------------------------------------------------------------- mask kernel
// Writes wT[so][t], t in padded-transposed layout:
//  L0: toff=0    pad=64 inall=6 wlo=0    ins=64
//  L1: toff=384  pad=68 inall=6 wlo=384  ins=67
//  L2: toff=792  pad=72 inall=8 wlo=786  ins=70
//  L3: toff=1368 pad=80 inall=8 wlo=1346 ins=78
//  L4: toff=2008 pad=88 inall=6 wlo=1970 ins=86
//  L5: toff=2536 pad=92 inall=6 wlo=2486 ins=90
//  F : toff=3088 pad=96 inall=1 wlo=3026 ins=94
__global__ __launch_bounds__(256) void eql_mask_kernel(
    const float* __restrict__ scores, const float* __restrict__ constw_base,
    const float* __restrict__ u0, const float* __restrict__ u1,
    float* __restrict__ wT)
{
  int idx = blockIdx.x * 256 + threadIdx.x;
  if (idx >= S_NUM * O_NUM * WPAD) return;
  int so = idx / WPAD;
  int t  = idx % WPAD;
  int o  = so % O_NUM;

  int toff, pad, inall, wlo, ins;
  if      (t < 384)  { toff = 0;    pad = 64; inall = 6; wlo = 0;    ins = 64; }
  else if (t < 792)  { toff = 384;  pad = 68; inall = 6; wlo = 384;  ins = 67; }
  else if (t < 1368) { toff = 792;  pad = 72; inall = 8; wlo = 786;  ins = 70; }
  else if (t < 2008) { toff = 1368; pad = 80; inall = 8; wlo = 1346; ins = 78; }
  else if (t < 2536) { toff = 2008; pad = 88; inall = 6; wlo = 1970; ins = 86; }
  else if (t < 3088) { toff = 2536; pad = 92; inall = 6; wlo = 2486; ins = 90; }
  else               { toff = 3088; pad = 96; inall = 1; wlo = 3026; ins = 94; }

  int l = t - toff;
  int e = l / pad;
  int d = l - e * pad;

  float val = 0.0f;
  if (d < ins) {
    int j   = wlo + d * inall + e;
    int oj  = o * WSHAPE + j;
    int soj = so * WSHAPE + j;
    float a0 = u0[soj], a1 = u1[soj];
    float noise = -logf(logf(a0 + EPS_F) / logf(a1 + EPS_F) + EPS_F);
    float sc = scores[oj];
    float cs = 1.0f / (1.0f + expf(-sc));
    float arg = (logf(cs + EPS_F) - logf(1.0f - cs + EPS_F) + noise) * TEMP_F;
    float soft = 1.0f / (1.0f + expf(-arg));
    float hard = (soft > 0.5f) ? 1.0f : 0.0f;
    val = constw_base[oj] * ((hard - soft) + soft);
  }
  wT[idx] = val;
}

// ---------------------------------------------------------------- ops
__device__ __forceinline__ float clip100(float x) {
  return fminf(fmaxf(x, -100.f), 100.f);
}
__device__ __forceinline__ float op_mul(float a, float b, float& r) {
  r += fmaxf(-100.f - a, 0.f) + fmaxf(a - 100.f, 0.f)
     + fmaxf(-100.f - b, 0.f) + fmaxf(b - 100.f, 0.f);
  return clip100(a) * clip100(b);
}
__device__ __forceinline__ float op_div(float a, float b, float& r) {
  r += fmaxf(0.01f - b, 0.f);
  return (b < 0.01f) ? 0.f : a / b;
}
__device__ __forceinline__ float op_log(float a, float& r) {
  r += fmaxf(0.001f - a, 0.f);
  return logf(fmaxf(a, 0.001f));
}
__device__ __forceinline__ float op_exp(float a, float& r) {
  r += fmaxf(-10.f - a, 0.f) + fmaxf(a - 4.f, 0.f);
  return expf(fminf(fmaxf(a, -10.f), 4.f));
}

// matmul vs transposed padded LDS weights. All indices compile-time.
// p[e] = bias[BLO+e] + sum_d wl[TOFF + e*INSP + d] * h[d]   (pads hit h==0)
template<int INSP, int INALL, int TOFF, int BLO>
__device__ __forceinline__ void do_mmt(const float* __restrict__ wl,
                                       const float (&h)[96], float (&p)[8]) {
#pragma unroll
  for (int e = 0; e < INALL; e++) p[e] = wl[BIAS_OFF + BLO + e];
#pragma unroll
  for (int e = 0; e < INALL; e++) {
#pragma unroll
    for (int d4 = 0; d4 < INSP / 4; d4++) {
      float4 wv = *reinterpret_cast<const float4*>(&wl[TOFF + e * INSP + d4 * 4]);
      p[e] = fmaf(wv.x, h[4 * d4 + 0], p[e]);
      p[e] = fmaf(wv.y, h[4 * d4 + 1], p[e]);
      p[e] = fmaf(wv.z, h[4 * d4 + 2], p[e]);
      p[e] = fmaf(wv.w, h[4 * d4 + 3], p[e]);
    }
  }
}

// ---------------------------------------------------------------- main kernel
__global__ __launch_bounds__(256, 3) void eql_main_kernel(
    const float* __restrict__ obs, const float* __restrict__ constb,
    const float* __restrict__ wT, float* __restrict__ out,
    double* __restrict__ regu_acc)
{
  __shared__ __align__(16) float wl[WPAD + 44];

  int blk = blockIdx.x;
  int chunk = blk & 15;
  int so = blk >> 4;             // 0..239
  int o = so % O_NUM;
  int s = so / O_NUM;

  // stage weights (3184 floats = 796 float4) + biases into LDS
  {
    const float4* src = reinterpret_cast<const float4*>(wT + (size_t)so * WPAD);
    float4* dst = reinterpret_cast<float4*>(wl);
    for (int i = threadIdx.x; i < WPAD / 4; i += 256) dst[i] = src[i];
    if (threadIdx.x < BSHAPE) wl[BIAS_OFF + threadIdx.x] = constb[o * BSHAPE + threadIdx.x];
  }
  __syncthreads();

  int b = chunk * 256 + threadIdx.x;

  float h[96];
  const float4* o4 = reinterpret_cast<const float4*>(obs + (size_t)b * NET_IN);
#pragma unroll
  for (int i = 0; i < 16; i++) {
    float4 v = o4[i];
    h[4 * i] = v.x; h[4 * i + 1] = v.y; h[4 * i + 2] = v.z; h[4 * i + 3] = v.w;
  }
#pragma unroll
  for (int i = 64; i < 96; i++) h[i] = 0.0f;   // pads must contribute 0

  float regu = 0.f;
  float p[8];

  { // layer 0: mul,mul,mul
    do_mmt<64, 6, 0, 0>(wl, h, p);
    h[64] = op_mul(p[0], p[1], regu);
    h[65] = op_mul(p[2], p[3], regu);
    h[66] = op_mul(p[4], p[5], regu);
  }
  { // layer 1: div,div,div
    do_mmt<68, 6, 384, 6>(wl, h, p);
    h[67] = op_div(p[0], p[1], regu);
    h[68] = op_div(p[2], p[3], regu);
    h[69] = op_div(p[4], p[5], regu);
  }
  { // layer 2: log,log,exp,exp,sin,sin,cos,cos
    do_mmt<72, 8, 792, 12>(wl, h, p);
    h[70] = op_log(p[0], regu);
    h[71] = op_log(p[1], regu);
    h[72] = op_exp(p[2], regu);
    h[73] = op_exp(p[3], regu);
    h[74] = sinf(p[4]);
    h[75] = sinf(p[5]);
    h[76] = cosf(p[6]);
    h[77] = cosf(p[7]);
  }
  { // layer 3: same
    do_mmt<80, 8, 1368, 20>(wl, h, p);
    h[78] = op_log(p[0], regu);
    h[79] = op_log(p[1], regu);
    h[80] = op_exp(p[2], regu);
    h[81] = op_exp(p[3], regu);
    h[82] = sinf(p[4]);
    h[83] = sinf(p[5]);
    h[84] = cosf(p[6]);
    h[85] = cosf(p[7]);
  }
  { // layer 4: mul,div,log,exp
    do_mmt<88, 6, 2008, 28>(wl, h, p);
    h[86] = op_mul(p[0], p[1], regu);
    h[87] = op_div(p[2], p[3], regu);
    h[88] = op_log(p[4], regu);
    h[89] = op_exp(p[5], regu);
  }
  { // layer 5: mul,div,log,exp
    do_mmt<92, 6, 2536, 34>(wl, h, p);
    h[90] = op_mul(p[0], p[1], regu);
    h[91] = op_div(p[2], p[3], regu);
    h[92] = op_log(p[4], regu);
    h[93] = op_exp(p[5], regu);
  }

  // final: ins=94 (pad 96), 1 output
  do_mmt<96, 1, 3088, 40>(wl, h, p);
  float res = p[0];

  out[((size_t)s * B_NUM + b) * O_NUM + o] = res;

  // ---- regu block reduction -> one f64 atomic per block
#pragma unroll
  for (int off = 32; off > 0; off >>= 1) regu += __shfl_down(regu, off);
  __shared__ float wsum[4];
  if ((threadIdx.x & 63) == 0) wsum[threadIdx.x >> 6] = regu;
  __syncthreads();
  if (threadIdx.x == 0) {
    float t = wsum[0] + wsum[1] + wsum[2] + wsum[3];
    atomicAdd(regu_acc, (double)t);
  }
}

// ---------------------------------------------------------------- finalize
__global__ void eql_finalize_kernel(const double* __restrict__ regu_acc,
                                    float* __restrict__ out)
{
  out[OUT_ELEMS] = (float)(*regu_acc / (double)OUT_ELEMS);
}

// ---------------------------------------------------------------- launch
extern "C" void kernel_launch(void* const* d_in, const int* in_sizes, int n_in,
                              void* d_out, int out_size, void* d_ws, size_t ws_size,
                              hipStream_t stream) {
  const float* obs    = (const float*)d_in[0];
  const float* scores = (const float*)d_in[1];
  const float* cwb    = (const float*)d_in[2];
  const float* constb = (const float*)d_in[3];
  const float* u0     = (const float*)d_in[4];
  const float* u1     = (const float*)d_in[5];
  float* out = (float*)d_out;

  double* regu = (double*)d_ws;                       // 8 B accumulator
  float*  wT   = (float*)((char*)d_ws + 256);         // 16*15*3184 floats ~ 2.9 MB

  hipMemsetAsync(regu, 0, sizeof(double), stream);

  int n_mask = S_NUM * O_NUM * WPAD;                  // 764160
  eql_mask_kernel<<<(n_mask + 255) / 256, 256, 0, stream>>>(scores, cwb, u0, u1, wT);

  eql_main_kernel<<<S_NUM * O_NUM * (B_NUM / 256), 256, 0, stream>>>(
      obs, constb, wT, out, regu);

  eql_finalize_kernel<<<1, 1, 0, stream>>>(regu, out);
}

// Round 4
// 806.928 us; speedup vs baseline: 2.5618x; 2.5618x over previous
//
#include <hip/hip_runtime.h>

// EQL forward, round 4: round-2 structure with the spill trigger removed.
// Round-3 lesson: __launch_bounds__(256,3) made the allocator target ~84 VGPRs
// and spill h[96] to scratch (FETCH 2.5GB / WRITE 4.1GB, 2ms). Plain
// __launch_bounds__(256) (round-1 config) compiled to 136 VGPRs, no spill.
//   kernel 1 (mask):  masked weights written TRANSPOSED+PADDED per (s,o) -> d_ws
//   kernel 2 (main):  one block per (s,o,chunk); weights staged to LDS once,
//                     read back as broadcast ds_read_b128. hidden[96] in VGPRs.
//   kernel 3 (fin):   out[983040] = regu_sum / (S*B*O)

#define S_NUM 16
#define O_NUM 15
#define B_NUM 4096
#define NET_IN 64
#define WSHAPE 3120
#define BSHAPE 41
#define WPAD 3184              // padded transposed size per (s,o)
#define BIAS_OFF WPAD          // bias offset inside LDS
#define TEMP_F 0.03f
#define EPS_F 1e-20f
#define OUT_ELEMS (S_NUM * B_NUM * O_NUM)   // 983040

// ---------------------------------------------------------------- mask kernel
// Writes wT[so][t], t in padded-transposed layout:
//  L0: toff=0    pad=64 inall=6 wlo=0    ins=64
//  L1: toff=384  pad=68 inall=6 wlo=384  ins=67
//  L2: toff=792  pad=72 inall=8 wlo=786  ins=70
//  L3: toff=1368 pad=80 inall=8 wlo=1346 ins=78
//  L4: toff=2008 pad=88 inall=6 wlo=1970 ins=86
//  L5: toff=2536 pad=92 inall=6 wlo=2486 ins=90
//  F : toff=3088 pad=96 inall=1 wlo=3026 ins=94
__global__ __launch_bounds__(256) void eql_mask_kernel(
    const float* __restrict__ scores, const float* __restrict__ constw_base,
    const float* __restrict__ u0, const float* __restrict__ u1,
    float* __restrict__ wT)
{
  int idx = blockIdx.x * 256 + threadIdx.x;
  if (idx >= S_NUM * O_NUM * WPAD) return;
  int so = idx / WPAD;
  int t  = idx % WPAD;
  int o  = so % O_NUM;

  int toff, pad, inall, wlo, ins;
  if      (t < 384)  { toff = 0;    pad = 64; inall = 6; wlo = 0;    ins = 64; }
  else if (t < 792)  { toff = 384;  pad = 68; inall = 6; wlo = 384;  ins = 67; }
  else if (t < 1368) { toff = 792;  pad = 72; inall = 8; wlo = 786;  ins = 70; }
  else if (t < 2008) { toff = 1368; pad = 80; inall = 8; wlo = 1346; ins = 78; }
  else if (t < 2536) { toff = 2008; pad = 88; inall = 6; wlo = 1970; ins = 86; }
  else if (t < 3088) { toff = 2536; pad = 92; inall = 6; wlo = 2486; ins = 90; }
  else               { toff = 3088; pad = 96; inall = 1; wlo = 3026; ins = 94; }

  int l = t - toff;
  int e = l / pad;
  int d = l - e * pad;

  float val = 0.0f;
  if (d < ins) {
    int j   = wlo + d * inall + e;
    int oj  = o * WSHAPE + j;
    int soj = so * WSHAPE + j;
    float a0 = u0[soj], a1 = u1[soj];
    float noise = -logf(logf(a0 + EPS_F) / logf(a1 + EPS_F) + EPS_F);
    float sc = scores[oj];
    float cs = 1.0f / (1.0f + expf(-sc));
    float arg = (logf(cs + EPS_F) - logf(1.0f - cs + EPS_F) + noise) * TEMP_F;
    float soft = 1.0f / (1.0f + expf(-arg));
    float hard = (soft > 0.5f) ? 1.0f : 0.0f;
    val = constw_base[oj] * ((hard - soft) + soft);
  }
  wT[idx] = val;
}

// ---------------------------------------------------------------- ops
__device__ __forceinline__ float clip100(float x) {
  return fminf(fmaxf(x, -100.f), 100.f);
}
__device__ __forceinline__ float op_mul(float a, float b, float& r) {
  r += fmaxf(-100.f - a, 0.f) + fmaxf(a - 100.f, 0.f)
     + fmaxf(-100.f - b, 0.f) + fmaxf(b - 100.f, 0.f);
  return clip100(a) * clip100(b);
}
__device__ __forceinline__ float op_div(float a, float b, float& r) {
  r += fmaxf(0.01f - b, 0.f);
  return (b < 0.01f) ? 0.f : a / b;
}
__device__ __forceinline__ float op_log(float a, float& r) {
  r += fmaxf(0.001f - a, 0.f);
  return logf(fmaxf(a, 0.001f));
}
__device__ __forceinline__ float op_exp(float a, float& r) {
  r += fmaxf(-10.f - a, 0.f) + fmaxf(a - 4.f, 0.f);
  return expf(fminf(fmaxf(a, -10.f), 4.f));
}

// matmul vs transposed padded LDS weights. All indices compile-time.
// p[e] = bias[BLO+e] + sum_d wl[TOFF + e*INSP + d] * h[d]   (pads hit h==0)
template<int INSP, int INALL, int TOFF, int BLO>
__device__ __forceinline__ void do_mmt(const float* __restrict__ wl,
                                       const float (&h)[96], float (&p)[8]) {
#pragma unroll
  for (int e = 0; e < INALL; e++) p[e] = wl[BIAS_OFF + BLO + e];
#pragma unroll
  for (int e = 0; e < INALL; e++) {
#pragma unroll
    for (int d4 = 0; d4 < INSP / 4; d4++) {
      float4 wv = *reinterpret_cast<const float4*>(&wl[TOFF + e * INSP + d4 * 4]);
      p[e] = fmaf(wv.x, h[4 * d4 + 0], p[e]);
      p[e] = fmaf(wv.y, h[4 * d4 + 1], p[e]);
      p[e] = fmaf(wv.z, h[4 * d4 + 2], p[e]);
      p[e] = fmaf(wv.w, h[4 * d4 + 3], p[e]);
    }
  }
}

// ---------------------------------------------------------------- main kernel
// NOTE: plain __launch_bounds__(256) — adding ",3" in round 3 triggered an
// 84-VGPR allocation target and spilled h[96] to scratch (2x slower).
__global__ __launch_bounds__(256) void eql_main_kernel(
    const float* __restrict__ obs, const float* __restrict__ constb,
    const float* __restrict__ wT, float* __restrict__ out,
    double* __restrict__ regu_acc)
{
  __shared__ __align__(16) float wl[WPAD + 44];

  int blk = blockIdx.x;
  int chunk = blk & 15;
  int so = blk >> 4;             // 0..239
  int o = so % O_NUM;
  int s = so / O_NUM;

  // stage weights (3184 floats = 796 float4) + biases into LDS
  {
    const float4* src = reinterpret_cast<const float4*>(wT + (size_t)so * WPAD);
    float4* dst = reinterpret_cast<float4*>(wl);
    for (int i = threadIdx.x; i < WPAD / 4; i += 256) dst[i] = src[i];
    if (threadIdx.x < BSHAPE) wl[BIAS_OFF + threadIdx.x] = constb[o * BSHAPE + threadIdx.x];
  }
  __syncthreads();

  int b = chunk * 256 + threadIdx.x;

  float h[96];
  const float4* o4 = reinterpret_cast<const float4*>(obs + (size_t)b * NET_IN);
#pragma unroll
  for (int i = 0; i < 16; i++) {
    float4 v = o4[i];
    h[4 * i] = v.x; h[4 * i + 1] = v.y; h[4 * i + 2] = v.z; h[4 * i + 3] = v.w;
  }
#pragma unroll
  for (int i = 64; i < 96; i++) h[i] = 0.0f;   // pads must contribute 0

  float regu = 0.f;
  float p[8];

  { // layer 0: mul,mul,mul
    do_mmt<64, 6, 0, 0>(wl, h, p);
    h[64] = op_mul(p[0], p[1], regu);
    h[65] = op_mul(p[2], p[3], regu);
    h[66] = op_mul(p[4], p[5], regu);
  }
  { // layer 1: div,div,div
    do_mmt<68, 6, 384, 6>(wl, h, p);
    h[67] = op_div(p[0], p[1], regu);
    h[68] = op_div(p[2], p[3], regu);
    h[69] = op_div(p[4], p[5], regu);
  }
  { // layer 2: log,log,exp,exp,sin,sin,cos,cos
    do_mmt<72, 8, 792, 12>(wl, h, p);
    h[70] = op_log(p[0], regu);
    h[71] = op_log(p[1], regu);
    h[72] = op_exp(p[2], regu);
    h[73] = op_exp(p[3], regu);
    h[74] = sinf(p[4]);
    h[75] = sinf(p[5]);
    h[76] = cosf(p[6]);
    h[77] = cosf(p[7]);
  }
  { // layer 3: same
    do_mmt<80, 8, 1368, 20>(wl, h, p);
    h[78] = op_log(p[0], regu);
    h[79] = op_log(p[1], regu);
    h[80] = op_exp(p[2], regu);
    h[81] = op_exp(p[3], regu);
    h[82] = sinf(p[4]);
    h[83] = sinf(p[5]);
    h[84] = cosf(p[6]);
    h[85] = cosf(p[7]);
  }
  { // layer 4: mul,div,log,exp
    do_mmt<88, 6, 2008, 28>(wl, h, p);
    h[86] = op_mul(p[0], p[1], regu);
    h[87] = op_div(p[2], p[3], regu);
    h[88] = op_log(p[4], regu);
    h[89] = op_exp(p[5], regu);
  }
  { // layer 5: mul,div,log,exp
    do_mmt<92, 6, 2536, 34>(wl, h, p);
    h[90] = op_mul(p[0], p[1], regu);
    h[91] = op_div(p[2], p[3], regu);
    h[92] = op_log(p[4], regu);
    h[93] = op_exp(p[5], regu);
  }

  // final: ins=94 (pad 96), 1 output
  do_mmt<96, 1, 3088, 40>(wl, h, p);
  float res = p[0];

  out[((size_t)s * B_NUM + b) * O_NUM + o] = res;

  // ---- regu block reduction -> one f64 atomic per block
#pragma unroll
  for (int off = 32; off > 0; off >>= 1) regu += __shfl_down(regu, off);
  __shared__ float wsum[4];
  if ((threadIdx.x & 63) == 0) wsum[threadIdx.x >> 6] = regu;
  __syncthreads();
  if (threadIdx.x == 0) {
    float t = wsum[0] + wsum[1] + wsum[2] + wsum[3];
    atomicAdd(regu_acc, (double)t);
  }
}

// ---------------------------------------------------------------- finalize
__global__ void eql_finalize_kernel(const double* __restrict__ regu_acc,
                                    float* __restrict__ out)
{
  out[OUT_ELEMS] = (float)(*regu_acc / (double)OUT_ELEMS);
}

// ---------------------------------------------------------------- launch
extern "C" void kernel_launch(void* const* d_in, const int* in_sizes, int n_in,
                              void* d_out, int out_size, void* d_ws, size_t ws_size,
                              hipStream_t stream) {
  const float* obs    = (const float*)d_in[0];
  const float* scores = (const float*)d_in[1];
  const float* cwb    = (const float*)d_in[2];
  const float* constb = (const float*)d_in[3];
  const float* u0     = (const float*)d_in[4];
  const float* u1     = (const float*)d_in[5];
  float* out = (float*)d_out;

  double* regu = (double*)d_ws;                       // 8 B accumulator
  float*  wT   = (float*)((char*)d_ws + 256);         // 16*15*3184 floats ~ 2.9 MB

  hipMemsetAsync(regu, 0, sizeof(double), stream);

  int n_mask = S_NUM * O_NUM * WPAD;                  // 764160
  eql_mask_kernel<<<(n_mask + 255) / 256, 256, 0, stream>>>(scores, cwb, u0, u1, wT);

  eql_main_kernel<<<S_NUM * O_NUM * (B_NUM / 256), 256, 0, stream>>>(
      obs, constb, wT, out, regu);

  eql_finalize_kernel<<<1, 1, 0, stream>>>(regu, out);
}

// Round 6
// 754.135 us; speedup vs baseline: 2.7411x; 1.0700x over previous
//
#include <hip/hip_runtime.h>

// EQL forward, round 5 (resubmitted — round-5 bench never acquired a GPU).
// Round-4 lesson: even with plain __launch_bounds__(256) the scheduler hoisted
// ~hundreds of unrolled ds_read_b128s, blew past 256 VGPRs and spilled h[96]
// (WRITE 1.08GB vs 4MB output). Fix: __builtin_amdgcn_sched_barrier(0) after
// each output-column accumulation caps the transient load window at <=24 b128.
//   kernel 1 (mask):  masked weights TRANSPOSED+PADDED per (s,o) -> d_ws
//   kernel 2 (main):  one block per (s,o,chunk); weights staged to LDS once,
//                     read back as broadcast ds_read_b128. hidden[96] in VGPRs.
//   kernel 3 (fin):   out[983040] = regu_sum / (S*B*O)

#define S_NUM 16
#define O_NUM 15
#define B_NUM 4096
#define NET_IN 64
#define WSHAPE 3120
#define BSHAPE 41
#define WPAD 3184              // padded transposed size per (s,o)
#define BIAS_OFF WPAD          // bias offset inside LDS
#define TEMP_F 0.03f
#define EPS_F 1e-20f
#define OUT_ELEMS (S_NUM * B_NUM * O_NUM)   // 983040

// ---------------------------------------------------------------- mask kernel
// Writes wT[so][t], t in padded-transposed layout:
//  L0: toff=0    pad=64 inall=6 wlo=0    ins=64
//  L1: toff=384  pad=68 inall=6 wlo=384  ins=67
//  L2: toff=792  pad=72 inall=8 wlo=786  ins=70
//  L3: toff=1368 pad=80 inall=8 wlo=1346 ins=78
//  L4: toff=2008 pad=88 inall=6 wlo=1970 ins=86
//  L5: toff=2536 pad=92 inall=6 wlo=2486 ins=90
//  F : toff=3088 pad=96 inall=1 wlo=3026 ins=94
__global__ __launch_bounds__(256) void eql_mask_kernel(
    const float* __restrict__ scores, const float* __restrict__ constw_base,
    const float* __restrict__ u0, const float* __restrict__ u1,
    float* __restrict__ wT)
{
  int idx = blockIdx.x * 256 + threadIdx.x;
  if (idx >= S_NUM * O_NUM * WPAD) return;
  int so = idx / WPAD;
  int t  = idx % WPAD;
  int o  = so % O_NUM;

  int toff, pad, inall, wlo, ins;
  if      (t < 384)  { toff = 0;    pad = 64; inall = 6; wlo = 0;    ins = 64; }
  else if (t < 792)  { toff = 384;  pad = 68; inall = 6; wlo = 384;  ins = 67; }
  else if (t < 1368) { toff = 792;  pad = 72; inall = 8; wlo = 786;  ins = 70; }
  else if (t < 2008) { toff = 1368; pad = 80; inall = 8; wlo = 1346; ins = 78; }
  else if (t < 2536) { toff = 2008; pad = 88; inall = 6; wlo = 1970; ins = 86; }
  else if (t < 3088) { toff = 2536; pad = 92; inall = 6; wlo = 2486; ins = 90; }
  else               { toff = 3088; pad = 96; inall = 1; wlo = 3026; ins = 94; }

  int l = t - toff;
  int e = l / pad;
  int d = l - e * pad;

  float val = 0.0f;
  if (d < ins) {
    int j   = wlo + d * inall + e;
    int oj  = o * WSHAPE + j;
    int soj = so * WSHAPE + j;
    float a0 = u0[soj], a1 = u1[soj];
    float noise = -logf(logf(a0 + EPS_F) / logf(a1 + EPS_F) + EPS_F);
    float sc = scores[oj];
    float cs = 1.0f / (1.0f + expf(-sc));
    float arg = (logf(cs + EPS_F) - logf(1.0f - cs + EPS_F) + noise) * TEMP_F;
    float soft = 1.0f / (1.0f + expf(-arg));
    float hard = (soft > 0.5f) ? 1.0f : 0.0f;
    val = constw_base[oj] * ((hard - soft) + soft);
  }
  wT[idx] = val;
}

// ---------------------------------------------------------------- ops
__device__ __forceinline__ float clip100(float x) {
  return fminf(fmaxf(x, -100.f), 100.f);
}
__device__ __forceinline__ float op_mul(float a, float b, float& r) {
  r += fmaxf(-100.f - a, 0.f) + fmaxf(a - 100.f, 0.f)
     + fmaxf(-100.f - b, 0.f) + fmaxf(b - 100.f, 0.f);
  return clip100(a) * clip100(b);
}
__device__ __forceinline__ float op_div(float a, float b, float& r) {
  r += fmaxf(0.01f - b, 0.f);
  return (b < 0.01f) ? 0.f : a / b;
}
__device__ __forceinline__ float op_log(float a, float& r) {
  r += fmaxf(0.001f - a, 0.f);
  return logf(fmaxf(a, 0.001f));
}
__device__ __forceinline__ float op_exp(float a, float& r) {
  r += fmaxf(-10.f - a, 0.f) + fmaxf(a - 4.f, 0.f);
  return expf(fminf(fmaxf(a, -10.f), 4.f));
}

// matmul vs transposed padded LDS weights. All indices compile-time.
// p[e] = bias[BLO+e] + sum_d wl[TOFF + e*INSP + d] * h[d]   (pads hit h==0)
// sched_barrier(0) after each e caps the scheduler's ds_read hoisting window
// (round-4 spill fix): worst region = 24 b128 loads + h[96] live ~ 200 VGPR.
template<int INSP, int INALL, int TOFF, int BLO>
__device__ __forceinline__ void do_mmt(const float* __restrict__ wl,
                                       const float (&h)[96], float (&p)[8]) {
#pragma unroll
  for (int e = 0; e < INALL; e++) {
    float acc = wl[BIAS_OFF + BLO + e];
#pragma unroll
    for (int d4 = 0; d4 < INSP / 4; d4++) {
      float4 wv = *reinterpret_cast<const float4*>(&wl[TOFF + e * INSP + d4 * 4]);
      acc = fmaf(wv.x, h[4 * d4 + 0], acc);
      acc = fmaf(wv.y, h[4 * d4 + 1], acc);
      acc = fmaf(wv.z, h[4 * d4 + 2], acc);
      acc = fmaf(wv.w, h[4 * d4 + 3], acc);
    }
    p[e] = acc;
    __builtin_amdgcn_sched_barrier(0);
  }
}

// ---------------------------------------------------------------- main kernel
// Plain __launch_bounds__(256): the ",3" variant (round 3) forced an 84-VGPR
// target and catastrophic spill; occupancy is taken care of by keeping
// natural VGPR use under ~200 via the sched_barrier fences.
__global__ __launch_bounds__(256) void eql_main_kernel(
    const float* __restrict__ obs, const float* __restrict__ constb,
    const float* __restrict__ wT, float* __restrict__ out,
    double* __restrict__ regu_acc)
{
  __shared__ __align__(16) float wl[WPAD + 44];

  int blk = blockIdx.x;
  int chunk = blk & 15;
  int so = blk >> 4;             // 0..239
  int o = so % O_NUM;
  int s = so / O_NUM;

  // stage weights (3184 floats = 796 float4) + biases into LDS
  {
    const float4* src = reinterpret_cast<const float4*>(wT + (size_t)so * WPAD);
    float4* dst = reinterpret_cast<float4*>(wl);
    for (int i = threadIdx.x; i < WPAD / 4; i += 256) dst[i] = src[i];
    if (threadIdx.x < BSHAPE) wl[BIAS_OFF + threadIdx.x] = constb[o * BSHAPE + threadIdx.x];
  }
  __syncthreads();

  int b = chunk * 256 + threadIdx.x;

  float h[96];
  const float4* o4 = reinterpret_cast<const float4*>(obs + (size_t)b * NET_IN);
#pragma unroll
  for (int i = 0; i < 16; i++) {
    float4 v = o4[i];
    h[4 * i] = v.x; h[4 * i + 1] = v.y; h[4 * i + 2] = v.z; h[4 * i + 3] = v.w;
  }
#pragma unroll
  for (int i = 64; i < 96; i++) h[i] = 0.0f;   // pads must contribute 0

  float regu = 0.f;
  float p[8];

  { // layer 0: mul,mul,mul
    do_mmt<64, 6, 0, 0>(wl, h, p);
    h[64] = op_mul(p[0], p[1], regu);
    h[65] = op_mul(p[2], p[3], regu);
    h[66] = op_mul(p[4], p[5], regu);
  }
  { // layer 1: div,div,div
    do_mmt<68, 6, 384, 6>(wl, h, p);
    h[67] = op_div(p[0], p[1], regu);
    h[68] = op_div(p[2], p[3], regu);
    h[69] = op_div(p[4], p[5], regu);
  }
  { // layer 2: log,log,exp,exp,sin,sin,cos,cos
    do_mmt<72, 8, 792, 12>(wl, h, p);
    h[70] = op_log(p[0], regu);
    h[71] = op_log(p[1], regu);
    h[72] = op_exp(p[2], regu);
    h[73] = op_exp(p[3], regu);
    h[74] = sinf(p[4]);
    h[75] = sinf(p[5]);
    h[76] = cosf(p[6]);
    h[77] = cosf(p[7]);
  }
  { // layer 3: same
    do_mmt<80, 8, 1368, 20>(wl, h, p);
    h[78] = op_log(p[0], regu);
    h[79] = op_log(p[1], regu);
    h[80] = op_exp(p[2], regu);
    h[81] = op_exp(p[3], regu);
    h[82] = sinf(p[4]);
    h[83] = sinf(p[5]);
    h[84] = cosf(p[6]);
    h[85] = cosf(p[7]);
  }
  { // layer 4: mul,div,log,exp
    do_mmt<88, 6, 2008, 28>(wl, h, p);
    h[86] = op_mul(p[0], p[1], regu);
    h[87] = op_div(p[2], p[3], regu);
    h[88] = op_log(p[4], regu);
    h[89] = op_exp(p[5], regu);
  }
  { // layer 5: mul,div,log,exp
    do_mmt<92, 6, 2536, 34>(wl, h, p);
    h[90] = op_mul(p[0], p[1], regu);
    h[91] = op_div(p[2], p[3], regu);
    h[92] = op_log(p[4], regu);
    h[93] = op_exp(p[5], regu);
  }

  // final: ins=94 (pad 96), 1 output
  do_mmt<96, 1, 3088, 40>(wl, h, p);
  float res = p[0];

  out[((size_t)s * B_NUM + b) * O_NUM + o] = res;

  // ---- regu block reduction -> one f64 atomic per block
#pragma unroll
  for (int off = 32; off > 0; off >>= 1) regu += __shfl_down(regu, off);
  __shared__ float wsum[4];
  if ((threadIdx.x & 63) == 0) wsum[threadIdx.x >> 6] = regu;
  __syncthreads();
  if (threadIdx.x == 0) {
    float t = wsum[0] + wsum[1] + wsum[2] + wsum[3];
    atomicAdd(regu_acc, (double)t);
  }
}

// ---------------------------------------------------------------- finalize
__global__ void eql_finalize_kernel(const double* __restrict__ regu_acc,
                                    float* __restrict__ out)
{
  out[OUT_ELEMS] = (float)(*regu_acc / (double)OUT_ELEMS);
}

// ---------------------------------------------------------------- launch
extern "C" void kernel_launch(void* const* d_in, const int* in_sizes, int n_in,
                              void* d_out, int out_size, void* d_ws, size_t ws_size,
                              hipStream_t stream) {
  const float* obs    = (const float*)d_in[0];
  const float* scores = (const float*)d_in[1];
  const float* cwb    = (const float*)d_in[2];
  const float* constb = (const float*)d_in[3];
  const float* u0     = (const float*)d_in[4];
  const float* u1     = (const float*)d_in[5];
  float* out = (float*)d_out;

  double* regu = (double*)d_ws;                       // 8 B accumulator
  float*  wT   = (float*)((char*)d_ws + 256);         // 16*15*3184 floats ~ 2.9 MB

  hipMemsetAsync(regu, 0, sizeof(double), stream);

  int n_mask = S_NUM * O_NUM * WPAD;                  // 764160
  eql_mask_kernel<<<(n_mask + 255) / 256, 256, 0, stream>>>(scores, cwb, u0, u1, wT);

  eql_main_kernel<<<S_NUM * O_NUM * (B_NUM / 256), 256, 0, stream>>>(
      obs, constb, wT, out, regu);

  eql_finalize_kernel<<<1, 1, 0, stream>>>(regu, out);
}